// Round 7
// baseline (143.119 us; speedup 1.0000x reference)
//
#include <hip/hip_runtime.h>
#include <math.h>

#define NC 16
#define DIM 16
#define LAYERS 6

typedef float v2f __attribute__((ext_vector_type(2)));

// ws layout (floats)
#define WS_LINV  0      // [NC][DIM][DIM] row-major, zeros above diag, 4096
#define WS_MU2   4096   // [NC][DIM] = Linv_c * mean_c, 256
#define WS_CST   4352   // [NC], 16
#define WS_ALPHA 4368   // [L][NC] = exp(log_alpha), 96
#define WS_TOT   4464

// One block per component, one wave per block (R6 version, kept).
__global__ void __launch_bounds__(64) prep_kernel(
    const float* __restrict__ cov, const float* __restrict__ log_alpha,
    const float* __restrict__ mean, float* __restrict__ ws) {
    __shared__ float A[DIM * 17];     // padded: A[i][j] at i*17+j
    __shared__ float B[DIM * DIM];    // Linv staged for mu2 matvec
    const int c = blockIdx.x;
    const int t = threadIdx.x;        // 0..63
    for (int k = t; k < DIM * DIM; k += 64) {
        int r = k >> 4, j = k & 15;
        A[r * 17 + j] = cov[c * 256 + k];
    }
    __syncthreads();
    const int i = t & 15;
    const bool act = t < 16;
    for (int k = 0; k < DIM; ++k) {
        if (act && i == k) A[k * 17 + k] = sqrtf(A[k * 17 + k]);
        __syncthreads();
        if (act && i > k) A[i * 17 + k] /= A[k * 17 + k];
        __syncthreads();
        if (act && i > k) {
            float lik = A[i * 17 + k];
            for (int j2 = k + 1; j2 <= i; ++j2)
                A[i * 17 + j2] -= lik * A[j2 * 17 + k];
        }
        __syncthreads();
    }
    // Forward substitution for column j of Linv — fully unrolled (VGPRs).
    const int j = i;
    float x[DIM];
    #pragma unroll
    for (int r = 0; r < DIM; ++r) {
        float s = (r == j) ? 1.0f : 0.0f;
        #pragma unroll
        for (int k = 0; k < r; ++k) s = fmaf(-A[r * 17 + k], x[k], s);
        x[r] = s / A[r * 17 + r];
    }
    if (act) {
        #pragma unroll
        for (int r = 0; r < DIM; ++r) {
            B[r * 16 + j] = x[r];
            ws[WS_LINV + c * 256 + r * 16 + j] = x[r];   // 0 above diag
        }
    }
    __syncthreads();
    if (t == 0) {
        float hld = 0.0f;
        #pragma unroll
        for (int r = 0; r < DIM; ++r) hld += __logf(A[r * 17 + r]);
        const float log2pi = 1.8378770664093453f;
        ws[WS_CST + c] = -0.5f * (float)DIM * log2pi - hld;
    }
    if (t < LAYERS) ws[WS_ALPHA + t * NC + c] = __expf(log_alpha[t * NC + c]);
    if (act) {
        float m2 = 0.0f;
        #pragma unroll
        for (int jj = 0; jj < DIM; ++jj)
            m2 = fmaf(B[i * 16 + jj], mean[c * DIM + jj], m2);
        ws[WS_MU2 + c * 16 + i] = m2;
    }
}

// d-ELIMINATED flow: phase 1 folds (zc-z0) straight into the r^2
// accumulator (temps die immediately); phase 2 rebuilds the update as
// zc <- (1+bh)*zc - bh*z0 so no 16-wide array lives across the
// sqrt->rcp chain. Target: kill the remat bloat behind VGPR_Count=24 /
// ~1600 VALU instrs per thread (hand count ~450).
__global__ void __launch_bounds__(1024, 4) density_kernel(
    const float* __restrict__ z, const float* __restrict__ z0,
    const float* __restrict__ beta, const float* __restrict__ ws,
    float* __restrict__ out, int N) {
    __shared__ float tile[64 * 17];
    const int tid = threadIdx.x;
    const int lane = tid & 63;
    const int c = __builtin_amdgcn_readfirstlane(tid >> 6);
    const int s = blockIdx.x * 64 + lane;
    const int sl = s < N ? s : N - 1;    // clamp; only final store is guarded

    v2f zc2[8];
    {
        const float4* zp = (const float4*)(z + (size_t)sl * DIM);
        float4 a0 = zp[0], a1 = zp[1], a2 = zp[2], a3 = zp[3];
        zc2[0] = (v2f){a0.x, a0.y}; zc2[1] = (v2f){a0.z, a0.w};
        zc2[2] = (v2f){a1.x, a1.y}; zc2[3] = (v2f){a1.z, a1.w};
        zc2[4] = (v2f){a2.x, a2.y}; zc2[5] = (v2f){a2.z, a2.w};
        zc2[6] = (v2f){a3.x, a3.y}; zc2[7] = (v2f){a3.z, a3.w};
    }

    float slj = 0.0f;
    #pragma unroll
    for (int l = 0; l < LAYERS; ++l) {
        const v2f* z0p = (const v2f*)(z0 + (l * NC + c) * DIM);  // uniform -> s_load
        // phase 1: r^2 — per-pair temp dies into the accumulator.
        v2f r2a = (v2f){0.0f, 0.0f}, r2b = (v2f){0.0f, 0.0f};
        #pragma unroll
        for (int k = 0; k < 8; ++k) {
            v2f t = zc2[k] - z0p[k];
            if (k & 1) r2b = __builtin_elementwise_fma(t, t, r2b);
            else       r2a = __builtin_elementwise_fma(t, t, r2a);
        }
        v2f r2v = r2a + r2b;
        float r = sqrtf(r2v.x + r2v.y);
        float al = ws[WS_ALPHA + l * NC + c];          // uniform -> s_load
        float b  = beta[l * NC + c];                   // uniform -> s_load
        float h  = __builtin_amdgcn_rcpf(al + r);
        float bh = b * h;
        float g  = 1.0f + bh;
        // phase 2: zc = g*zc - bh*z0  (z0 from SGPRs; no saved d[] needed)
        v2f g2   = (v2f){g, g};
        v2f nbh2 = (v2f){-bh, -bh};
        #pragma unroll
        for (int k = 0; k < 8; ++k)
            zc2[k] = __builtin_elementwise_fma(g2, zc2[k], nbh2 * z0p[k]);
        float rh = r * h;
        float t2 = fmaf(-bh, rh, bh);                  // bh - b*r*h*h
        slj += 15.0f * __logf(g) + __logf(1.0f + t2);
    }

    // q = || Linv_c*zk - mu2_c ||^2, packed over j (zeros above diag round
    // odd row lengths up to a whole pair).
    const v2f* Li2 = (const v2f*)(ws + WS_LINV + c * 256);  // row i: Li2[i*8+jj]
    const float* m2 = ws + WS_MU2 + c * 16;
    float q = 0.0f;
    #pragma unroll
    for (int i = 0; i < DIM; ++i) {
        v2f acc2 = (v2f){0.0f, 0.0f};
        #pragma unroll
        for (int jj = 0; jj <= (i >> 1); ++jj)
            acc2 = __builtin_elementwise_fma(Li2[i * 8 + jj], zc2[jj], acc2);
        float acc = (acc2.x + acc2.y) - m2[i];
        q = fmaf(acc, acc, q);
    }

    float res = ws[WS_CST + c] + fmaf(-0.5f, q, slj);
    if (res != res) res = -INFINITY;     // NaN -> -inf (reference semantics)

    // Transpose through LDS so the global store is fully coalesced.
    tile[lane * 17 + c] = res;
    __syncthreads();
    const int srow = tid >> 4, col = tid & 15;
    const int gs = blockIdx.x * 64 + srow;
    if (gs < N) out[(size_t)gs * NC + col] = tile[srow * 17 + col];
}

extern "C" void kernel_launch(void* const* d_in, const int* in_sizes, int n_in,
                              void* d_out, int out_size, void* d_ws, size_t ws_size,
                              hipStream_t stream) {
    const float* z    = (const float*)d_in[0];
    const float* z0   = (const float*)d_in[1];
    const float* la   = (const float*)d_in[2];
    const float* beta = (const float*)d_in[3];
    const float* mean = (const float*)d_in[4];
    const float* cov  = (const float*)d_in[5];
    float* out = (float*)d_out;
    float* ws  = (float*)d_ws;
    const int N = in_sizes[0] / DIM;

    hipLaunchKernelGGL(prep_kernel, dim3(NC), dim3(64), 0, stream, cov, la, mean, ws);
    const int nb = (N + 63) / 64;
    hipLaunchKernelGGL(density_kernel, dim3(nb), dim3(1024), 0, stream,
                       z, z0, beta, ws, out, N);
}

// Round 8
// 140.887 us; speedup vs baseline: 1.0158x; 1.0158x over previous
//
#include <hip/hip_runtime.h>
#include <math.h>

#define NC 16
#define DIM 16
#define LAYERS 6

typedef float v2f __attribute__((ext_vector_type(2)));

// ws layout (floats)
#define WS_LINV  0      // [NC][DIM][DIM] row-major, zeros above diag, 4096
#define WS_MU2   4096   // [NC][DIM] = Linv_c * mean_c, 256
#define WS_CST   4352   // [NC], 16
#define WS_ALPHA 4368   // [L][NC] = exp(log_alpha), 96
#define WS_TOT   4464

// One block per component, one wave per block (R6 version, kept).
__global__ void __launch_bounds__(64) prep_kernel(
    const float* __restrict__ cov, const float* __restrict__ log_alpha,
    const float* __restrict__ mean, float* __restrict__ ws) {
    __shared__ float A[DIM * 17];     // padded: A[i][j] at i*17+j
    __shared__ float B[DIM * DIM];    // Linv staged for mu2 matvec
    const int c = blockIdx.x;
    const int t = threadIdx.x;        // 0..63
    for (int k = t; k < DIM * DIM; k += 64) {
        int r = k >> 4, j = k & 15;
        A[r * 17 + j] = cov[c * 256 + k];
    }
    __syncthreads();
    const int i = t & 15;
    const bool act = t < 16;
    for (int k = 0; k < DIM; ++k) {
        if (act && i == k) A[k * 17 + k] = sqrtf(A[k * 17 + k]);
        __syncthreads();
        if (act && i > k) A[i * 17 + k] /= A[k * 17 + k];
        __syncthreads();
        if (act && i > k) {
            float lik = A[i * 17 + k];
            for (int j2 = k + 1; j2 <= i; ++j2)
                A[i * 17 + j2] -= lik * A[j2 * 17 + k];
        }
        __syncthreads();
    }
    // Forward substitution for column j of Linv — fully unrolled (VGPRs).
    const int j = i;
    float x[DIM];
    #pragma unroll
    for (int r = 0; r < DIM; ++r) {
        float s = (r == j) ? 1.0f : 0.0f;
        #pragma unroll
        for (int k = 0; k < r; ++k) s = fmaf(-A[r * 17 + k], x[k], s);
        x[r] = s / A[r * 17 + r];
    }
    if (act) {
        #pragma unroll
        for (int r = 0; r < DIM; ++r) {
            B[r * 16 + j] = x[r];
            ws[WS_LINV + c * 256 + r * 16 + j] = x[r];   // 0 above diag
        }
    }
    __syncthreads();
    if (t == 0) {
        float hld = 0.0f;
        #pragma unroll
        for (int r = 0; r < DIM; ++r) hld += __logf(A[r * 17 + r]);
        const float log2pi = 1.8378770664093453f;
        ws[WS_CST + c] = -0.5f * (float)DIM * log2pi - hld;
    }
    if (t < LAYERS) ws[WS_ALPHA + t * NC + c] = __expf(log_alpha[t * NC + c]);
    if (act) {
        float m2 = 0.0f;
        #pragma unroll
        for (int jj = 0; jj < DIM; ++jj)
            m2 = fmaf(B[i * 16 + jj], mean[c * DIM + jj], m2);
        ws[WS_MU2 + c * 16 + i] = m2;
    }
}

// R5 math (best measured: 63.1us) with a BARRIER-FREE epilogue: the LDS
// transpose + __syncthreads existed only to coalesce the final 4B store.
// Stores are fire-and-forget (12.5 MB total ~ 2us of HBM even amplified),
// while the barrier forces all 16 waves of the block to rendezvous at the
// end — the suspected ~20% VALU idle. Direct strided store instead.
__global__ void __launch_bounds__(1024, 4) density_kernel(
    const float* __restrict__ z, const float* __restrict__ z0,
    const float* __restrict__ beta, const float* __restrict__ ws,
    float* __restrict__ out, int N) {
    const int tid = threadIdx.x;
    const int lane = tid & 63;
    const int c = __builtin_amdgcn_readfirstlane(tid >> 6);
    const int s = blockIdx.x * 64 + lane;
    const int sl = s < N ? s : N - 1;    // clamp; store is guarded

    v2f zc2[8];
    {
        const float4* zp = (const float4*)(z + (size_t)sl * DIM);
        float4 a0 = zp[0], a1 = zp[1], a2 = zp[2], a3 = zp[3];
        zc2[0] = (v2f){a0.x, a0.y}; zc2[1] = (v2f){a0.z, a0.w};
        zc2[2] = (v2f){a1.x, a1.y}; zc2[3] = (v2f){a1.z, a1.w};
        zc2[4] = (v2f){a2.x, a2.y}; zc2[5] = (v2f){a2.z, a2.w};
        zc2[6] = (v2f){a3.x, a3.y}; zc2[7] = (v2f){a3.z, a3.w};
    }

    float slj = 0.0f;
    #pragma unroll
    for (int l = 0; l < LAYERS; ++l) {
        const v2f* z0p = (const v2f*)(z0 + (l * NC + c) * DIM);  // uniform -> s_load
        v2f d2[8];
        v2f r2a = (v2f){0.0f, 0.0f}, r2b = (v2f){0.0f, 0.0f};
        #pragma unroll
        for (int k = 0; k < 8; ++k) {
            d2[k] = zc2[k] - z0p[k];
            if (k & 1) r2b = __builtin_elementwise_fma(d2[k], d2[k], r2b);
            else       r2a = __builtin_elementwise_fma(d2[k], d2[k], r2a);
        }
        v2f r2v = r2a + r2b;
        float r2 = r2v.x + r2v.y;
        float r = sqrtf(r2);
        float al = ws[WS_ALPHA + l * NC + c];          // uniform -> s_load
        float b  = beta[l * NC + c];                   // uniform -> s_load
        float h  = __builtin_amdgcn_rcpf(al + r);
        float bh = b * h;
        v2f bh2 = (v2f){bh, bh};
        #pragma unroll
        for (int k = 0; k < 8; ++k)
            zc2[k] = __builtin_elementwise_fma(bh2, d2[k], zc2[k]);
        float t2 = fmaf(-(b * r * h), h, bh);
        slj += 15.0f * __logf(1.0f + bh) + __logf(1.0f + t2);
    }

    // q = || Linv_c*zk - mu2_c ||^2, packed over j (zeros above diag round
    // odd row lengths up to a whole pair).
    const v2f* Li2 = (const v2f*)(ws + WS_LINV + c * 256);  // row i: Li2[i*8+jj]
    const float* m2 = ws + WS_MU2 + c * 16;
    float q = 0.0f;
    #pragma unroll
    for (int i = 0; i < DIM; ++i) {
        v2f acc2 = (v2f){0.0f, 0.0f};
        #pragma unroll
        for (int jj = 0; jj <= (i >> 1); ++jj)
            acc2 = __builtin_elementwise_fma(Li2[i * 8 + jj], zc2[jj], acc2);
        float acc = (acc2.x + acc2.y) - m2[i];
        q = fmaf(acc, acc, q);
    }

    float res = ws[WS_CST + c] + fmaf(-0.5f, q, slj);
    if (res != res) res = -INFINITY;     // NaN -> -inf (reference semantics)

    // Direct strided store: 64 lanes x 64B stride = 32 lines/wave, but all
    // 16 c-waves of the block hit the same lines; L2 sector-merges. No
    // barrier, no LDS — waves retire independently.
    if (s < N) out[(size_t)s * NC + c] = res;
}

extern "C" void kernel_launch(void* const* d_in, const int* in_sizes, int n_in,
                              void* d_out, int out_size, void* d_ws, size_t ws_size,
                              hipStream_t stream) {
    const float* z    = (const float*)d_in[0];
    const float* z0   = (const float*)d_in[1];
    const float* la   = (const float*)d_in[2];
    const float* beta = (const float*)d_in[3];
    const float* mean = (const float*)d_in[4];
    const float* cov  = (const float*)d_in[5];
    float* out = (float*)d_out;
    float* ws  = (float*)d_ws;
    const int N = in_sizes[0] / DIM;

    hipLaunchKernelGGL(prep_kernel, dim3(NC), dim3(64), 0, stream, cov, la, mean, ws);
    const int nb = (N + 63) / 64;
    hipLaunchKernelGGL(density_kernel, dim3(nb), dim3(1024), 0, stream,
                       z, z0, beta, ws, out, N);
}

// Round 9
// 123.207 us; speedup vs baseline: 1.1616x; 1.1435x over previous
//
#include <hip/hip_runtime.h>
#include <math.h>

#define NC 16
#define DIM 16
#define LAYERS 6

typedef float v2f __attribute__((ext_vector_type(2)));

// ws layout (floats)
#define WS_LINV  0      // [NC][DIM][DIM] row-major, zeros above diag, 4096
#define WS_MU2   4096   // [NC][DIM] = Linv_c * mean_c, 256
#define WS_CST   4352   // [NC], 16
#define WS_ALPHA 4368   // [L][NC] = exp(log_alpha), 96
#define WS_TOT   4464

// One block per component, one wave per block (R6 version, kept).
__global__ void __launch_bounds__(64) prep_kernel(
    const float* __restrict__ cov, const float* __restrict__ log_alpha,
    const float* __restrict__ mean, float* __restrict__ ws) {
    __shared__ float A[DIM * 17];     // padded: A[i][j] at i*17+j
    __shared__ float B[DIM * DIM];    // Linv staged for mu2 matvec
    const int c = blockIdx.x;
    const int t = threadIdx.x;        // 0..63
    for (int k = t; k < DIM * DIM; k += 64) {
        int r = k >> 4, j = k & 15;
        A[r * 17 + j] = cov[c * 256 + k];
    }
    __syncthreads();
    const int i = t & 15;
    const bool act = t < 16;
    for (int k = 0; k < DIM; ++k) {
        if (act && i == k) A[k * 17 + k] = sqrtf(A[k * 17 + k]);
        __syncthreads();
        if (act && i > k) A[i * 17 + k] /= A[k * 17 + k];
        __syncthreads();
        if (act && i > k) {
            float lik = A[i * 17 + k];
            for (int j2 = k + 1; j2 <= i; ++j2)
                A[i * 17 + j2] -= lik * A[j2 * 17 + k];
        }
        __syncthreads();
    }
    // Forward substitution for column j of Linv — fully unrolled (VGPRs).
    const int j = i;
    float x[DIM];
    #pragma unroll
    for (int r = 0; r < DIM; ++r) {
        float s = (r == j) ? 1.0f : 0.0f;
        #pragma unroll
        for (int k = 0; k < r; ++k) s = fmaf(-A[r * 17 + k], x[k], s);
        x[r] = s / A[r * 17 + r];
    }
    if (act) {
        #pragma unroll
        for (int r = 0; r < DIM; ++r) {
            B[r * 16 + j] = x[r];
            ws[WS_LINV + c * 256 + r * 16 + j] = x[r];   // 0 above diag
        }
    }
    __syncthreads();
    if (t == 0) {
        float hld = 0.0f;
        #pragma unroll
        for (int r = 0; r < DIM; ++r) hld += __logf(A[r * 17 + r]);
        const float log2pi = 1.8378770664093453f;
        ws[WS_CST + c] = -0.5f * (float)DIM * log2pi - hld;
    }
    if (t < LAYERS) ws[WS_ALPHA + t * NC + c] = __expf(log_alpha[t * NC + c]);
    if (act) {
        float m2 = 0.0f;
        #pragma unroll
        for (int jj = 0; jj < DIM; ++jj)
            m2 = fmaf(B[i * 16 + jj], mean[c * DIM + jj], m2);
        ws[WS_MU2 + c * 16 + i] = m2;
    }
}

// R5 math with: raw v_sqrt_f32 (no IEEE fixup seq — r^2 in [1e-2,1e3]),
// log2-domain Jacobian accumulation (one x ln2 at the end), and 256-thread
// blocks (grid.y=4 covers c in groups of 4) so up to 8 blocks/CU — fixes
// the 16-wave-block occupancy granularity (71% in R5/R6).
__global__ void __launch_bounds__(256) density_kernel(
    const float* __restrict__ z, const float* __restrict__ z0,
    const float* __restrict__ beta, const float* __restrict__ ws,
    float* __restrict__ out, int N) {
    __shared__ float tile[64 * 5];
    const int tid = threadIdx.x;
    const int lane = tid & 63;
    const int wv = tid >> 6;                       // 0..3
    const int c = __builtin_amdgcn_readfirstlane(blockIdx.y * 4 + wv);
    const int s = blockIdx.x * 64 + lane;
    const int sl = s < N ? s : N - 1;    // clamp; only final store is guarded

    v2f zc2[8];
    {
        const float4* zp = (const float4*)(z + (size_t)sl * DIM);
        float4 a0 = zp[0], a1 = zp[1], a2 = zp[2], a3 = zp[3];
        zc2[0] = (v2f){a0.x, a0.y}; zc2[1] = (v2f){a0.z, a0.w};
        zc2[2] = (v2f){a1.x, a1.y}; zc2[3] = (v2f){a1.z, a1.w};
        zc2[4] = (v2f){a2.x, a2.y}; zc2[5] = (v2f){a2.z, a2.w};
        zc2[6] = (v2f){a3.x, a3.y}; zc2[7] = (v2f){a3.z, a3.w};
    }

    float slj2 = 0.0f;                   // log2-domain accumulator
    #pragma unroll
    for (int l = 0; l < LAYERS; ++l) {
        const v2f* z0p = (const v2f*)(z0 + (l * NC + c) * DIM);  // uniform -> s_load
        v2f d2[8];
        v2f r2a = (v2f){0.0f, 0.0f}, r2b = (v2f){0.0f, 0.0f};
        #pragma unroll
        for (int k = 0; k < 8; ++k) {
            d2[k] = zc2[k] - z0p[k];
            if (k & 1) r2b = __builtin_elementwise_fma(d2[k], d2[k], r2b);
            else       r2a = __builtin_elementwise_fma(d2[k], d2[k], r2a);
        }
        v2f r2v = r2a + r2b;
        float r = __builtin_amdgcn_sqrtf(r2v.x + r2v.y);  // raw v_sqrt_f32
        float al = ws[WS_ALPHA + l * NC + c];             // uniform -> s_load
        float b  = beta[l * NC + c];                      // uniform -> s_load
        float h  = __builtin_amdgcn_rcpf(al + r);
        float bh = b * h;
        v2f bh2 = (v2f){bh, bh};
        #pragma unroll
        for (int k = 0; k < 8; ++k)
            zc2[k] = __builtin_elementwise_fma(bh2, d2[k], zc2[k]);
        float t2 = fmaf(-(b * r * h), h, bh);             // bh - b*r*h*h
        // log2 domain: v_log_f32 is log2; scale once at the end.
        float lg = __builtin_amdgcn_logf(1.0f + bh);
        float lt = __builtin_amdgcn_logf(1.0f + t2);
        slj2 = fmaf(15.0f, lg, slj2) + lt;
    }

    // q = || Linv_c*zk - mu2_c ||^2, packed over j (zeros above diag round
    // odd row lengths up to a whole pair).
    const v2f* Li2 = (const v2f*)(ws + WS_LINV + c * 256);  // row i: Li2[i*8+jj]
    const float* m2 = ws + WS_MU2 + c * 16;
    float q = 0.0f;
    #pragma unroll
    for (int i = 0; i < DIM; ++i) {
        v2f acc2 = (v2f){0.0f, 0.0f};
        #pragma unroll
        for (int jj = 0; jj <= (i >> 1); ++jj)
            acc2 = __builtin_elementwise_fma(Li2[i * 8 + jj], zc2[jj], acc2);
        float acc = (acc2.x + acc2.y) - m2[i];
        q = fmaf(acc, acc, q);
    }

    const float ln2 = 0.6931471805599453f;
    float res = ws[WS_CST + c] + fmaf(-0.5f, q, slj2 * ln2);
    if (res != res) res = -INFINITY;     // NaN -> -inf (reference semantics)

    // Transpose through LDS (4-c group) for merged stores; barrier is only
    // 4 waves now.
    tile[lane * 5 + wv] = res;
    __syncthreads();
    const int srow = tid >> 2, col = tid & 3;
    const int gs = blockIdx.x * 64 + srow;
    if (gs < N) out[(size_t)gs * NC + blockIdx.y * 4 + col] = tile[srow * 5 + col];
}

extern "C" void kernel_launch(void* const* d_in, const int* in_sizes, int n_in,
                              void* d_out, int out_size, void* d_ws, size_t ws_size,
                              hipStream_t stream) {
    const float* z    = (const float*)d_in[0];
    const float* z0   = (const float*)d_in[1];
    const float* la   = (const float*)d_in[2];
    const float* beta = (const float*)d_in[3];
    const float* mean = (const float*)d_in[4];
    const float* cov  = (const float*)d_in[5];
    float* out = (float*)d_out;
    float* ws  = (float*)d_ws;
    const int N = in_sizes[0] / DIM;

    hipLaunchKernelGGL(prep_kernel, dim3(NC), dim3(64), 0, stream, cov, la, mean, ws);
    const int nb = (N + 63) / 64;
    hipLaunchKernelGGL(density_kernel, dim3(nb, 4), dim3(256), 0, stream,
                       z, z0, beta, ws, out, N);
}